// Round 14
// baseline (1103.736 us; speedup 1.0000x reference)
//
#include <hip/hip_runtime.h>
#include <stdint.h>

#define NB 8
#define NN 4096
#define NP 1024
#define NSAMP 32
#define CIN 64
#define C3 128
#define XS 20

typedef float v2f __attribute__((ext_vector_type(2)));

__device__ __forceinline__ float lo2f(unsigned int u) { return __uint_as_float(u << 16); }
__device__ __forceinline__ float hi2f(unsigned int u) { return __uint_as_float(u & 0xffff0000u); }
__device__ __forceinline__ unsigned short f2b(float f) {
  unsigned int u = __float_as_uint(f);
  unsigned int r = u + 0x7fffu + ((u >> 16) & 1u);
  return (unsigned short)(r >> 16);
}
__device__ __forceinline__ unsigned int packbf(float a, float b) {
  return (unsigned int)f2b(a) | ((unsigned int)f2b(b) << 16);
}

#define FMAXD(v, ctrl)                                                     \
  do {                                                                     \
    int _x = __float_as_int(v);                                            \
    int _m = __builtin_amdgcn_update_dpp(_x, _x, (ctrl), 0xf, 0xf, false); \
    (v) = fmaxf((v), __int_as_float(_m));                                  \
  } while (0)

// Single fused launch. Blocks 0..7: R12 FPS core + progressive publication of
// fps indices (release every 16 iters). Blocks 8..1031: R11 fused ballq+mlp
// consumers, each waiting (acquire spin) for its 8 centers to be published.
// LDS is a manual union: fps needs 50.3 KB, consumer 63 KB -> 64512 B static.
__global__ __launch_bounds__(256, 1) void fused_kernel(
    const float* __restrict__ xyz, const float* __restrict__ points,
    unsigned short* __restrict__ fps_g, int* __restrict__ progress,
    const float* __restrict__ W0, const float* __restrict__ b0,
    const float* __restrict__ g0, const float* __restrict__ be0,
    const float* __restrict__ W1, const float* __restrict__ b1,
    const float* __restrict__ g1, const float* __restrict__ be1,
    const float* __restrict__ W2, const float* __restrict__ b2,
    const float* __restrict__ g2, const float* __restrict__ be2,
    float* __restrict__ out_xyz, float* __restrict__ out_feat) {
  __shared__ __align__(16) unsigned char smem[64512];
  const int blk = blockIdx.x;
  const int tid = threadIdx.x;
  if (blk < NB) {
    // ================= FPS role (R12 core, 4 waves x 16 pts) ================
#pragma clang fp contract(off)
#if __has_builtin(__builtin_amdgcn_s_setprio)
    __builtin_amdgcn_s_setprio(3);
#endif
    float* sx = (float*)smem;
    float* sy = sx + NN;
    float* sz = sy + NN;
    unsigned long long* slotmem = (unsigned long long*)(smem + 49152);  // [2][4]
    unsigned short* scidx = (unsigned short*)(smem + 49152 + 64);
    const int b = blk;
    const int lane = tid & 63;
    const int wv = tid >> 6;
    const float* xb = xyz + (size_t)b * NN * 3;
    for (int i = tid; i < NN; i += 256) {
      sx[i] = xb[3 * i + 0];
      sy[i] = xb[3 * i + 1];
      sz[i] = xb[3 * i + 2];
    }
    if (tid < 8) slotmem[tid] = 0ull;  // k-field 0
    if (tid == 0) {
      scidx[0] = 0;
      fps_g[b * NP] = 0;  // center 0 published with first release
    }
    __syncthreads();
    v2f px[8], py[8], pz[8], dd[8];
#pragma unroll
    for (int i = 0; i < 8; ++i) {
      int i0 = tid * 16 + 2 * i;
      px[i] = (v2f){sx[i0], sx[i0 + 1]};
      py[i] = (v2f){sy[i0], sy[i0 + 1]};
      pz[i] = (v2f){sz[i0], sz[i0 + 1]};
      dd[i] = (v2f){1e10f, 1e10f};
    }
    float qx = sx[0], qy = sy[0], qz = sz[0];
    for (int k = 1; k < NP; ++k) {
      v2f q2x = (v2f){qx, qx};
      v2f q2y = (v2f){qy, qy};
      v2f q2z = (v2f){qz, qz};
#pragma unroll
      for (int i = 0; i < 8; ++i) {
        v2f dx = px[i] - q2x;
        v2f dy = py[i] - q2y;
        v2f dz = pz[i] - q2z;
        v2f xx = dx * dx;
        v2f yy = dy * dy;
        v2f zz = dz * dz;
        v2f s = xx + yy;
        v2f d = s + zz;  // per-element np order, contract off
        dd[i] = __builtin_elementwise_min(dd[i], d);
      }
      float v1[8]; int j1[8];
#pragma unroll
      for (int i = 0; i < 8; ++i) {
        bool g = dd[i].y > dd[i].x;
        v1[i] = g ? dd[i].y : dd[i].x;
        j1[i] = 2 * i + (g ? 1 : 0);
      }
      float v2a[4]; int j2a[4];
#pragma unroll
      for (int i = 0; i < 4; ++i) {
        bool g = v1[2 * i + 1] > v1[2 * i];
        v2a[i] = g ? v1[2 * i + 1] : v1[2 * i];
        j2a[i] = g ? j1[2 * i + 1] : j1[2 * i];
      }
      float v3[2]; int j3[2];
#pragma unroll
      for (int i = 0; i < 2; ++i) {
        bool g = v2a[2 * i + 1] > v2a[2 * i];
        v3[i] = g ? v2a[2 * i + 1] : v2a[2 * i];
        j3[i] = g ? j2a[2 * i + 1] : j2a[2 * i];
      }
      bool g0 = v3[1] > v3[0];
      float bestv = g0 ? v3[1] : v3[0];
      int gi = tid * 16 + (g0 ? j3[1] : j3[0]);
      float m = bestv;
      FMAXD(m, 0x111); FMAXD(m, 0x112); FMAXD(m, 0x114);
      FMAXD(m, 0x118); FMAXD(m, 0x142); FMAXD(m, 0x143);
      float wmax = __int_as_float(__builtin_amdgcn_readlane(__float_as_int(m), 63));
      unsigned long long ball = __ballot(bestv == wmax);
      int wl = __ffsll((long long)ball) - 1;  // lowest lane == lowest index
      int widx = __builtin_amdgcn_readlane(gi, wl);
      unsigned long long rec =
          ((unsigned long long)(((unsigned)k << 12) | (unsigned)widx) << 32) |
          (unsigned long long)__float_as_uint(wmax);
      unsigned long long* sl = slotmem + (k & 1) * 4;
      if (lane == 0) sl[wv] = rec;
      asm volatile("" ::: "memory");
      unsigned long long s0, s1, s2, s3;
      for (;;) {
        ulonglong2 pa = *(const ulonglong2*)(sl);
        ulonglong2 pb = *(const ulonglong2*)(sl + 2);
        s0 = pa.x; s1 = pa.y; s2 = pb.x; s3 = pb.y;
        if ((unsigned)(s0 >> 44) == (unsigned)k &&
            (unsigned)(s1 >> 44) == (unsigned)k &&
            (unsigned)(s2 >> 44) == (unsigned)k &&
            (unsigned)(s3 >> 44) == (unsigned)k)
          break;
        asm volatile("" ::: "memory");
      }
      float bv = __uint_as_float((unsigned)s0);
      int wi = (int)((s0 >> 32) & 0xFFFu);
      {
        float v = __uint_as_float((unsigned)s1);
        int iw = (int)((s1 >> 32) & 0xFFFu);
        bool g = v > bv; bv = g ? v : bv; wi = g ? iw : wi;
      }
      {
        float v = __uint_as_float((unsigned)s2);
        int iw = (int)((s2 >> 32) & 0xFFFu);
        bool g = v > bv; bv = g ? v : bv; wi = g ? iw : wi;
      }
      {
        float v = __uint_as_float((unsigned)s3);
        int iw = (int)((s3 >> 32) & 0xFFFu);
        bool g = v > bv; bv = g ? v : bv; wi = g ? iw : wi;
      }
      qx = sx[wi]; qy = sy[wi]; qz = sz[wi];  // broadcast reads
      if (tid == 0) {
        scidx[k] = (unsigned short)wi;
        fps_g[b * NP + k] = (unsigned short)wi;  // fire-and-forget
        if ((k & 15) == 15)
          __hip_atomic_store(&progress[b], k, __ATOMIC_RELEASE,
                             __HIP_MEMORY_SCOPE_AGENT);
      }
    }
    __syncthreads();
    for (int i = tid; i < NP; i += 256) {
      int id = scidx[i];
      out_xyz[((size_t)b * NP + i) * 3 + 0] = sx[id];
      out_xyz[((size_t)b * NP + i) * 3 + 1] = sy[id];
      out_xyz[((size_t)b * NP + i) * 3 + 2] = sz[id];
    }
    return;
  }
  // ================= Consumer role: ballq + gather + MLP + max =============
  const int j = blk - NB;            // 0..1023
  const int bq = j >> 7;             // batch
  const int smax = (j & 127) * 8 + 7;  // last center this block needs
  if (tid == 0) {
    for (;;) {
      int p = __hip_atomic_load(&progress[bq], __ATOMIC_ACQUIRE,
                                __HIP_MEMORY_SCOPE_AGENT);
      if (p >= smax) break;
#if __has_builtin(__builtin_amdgcn_s_sleep)
      __builtin_amdgcn_s_sleep(8);
#endif
    }
  }
  __syncthreads();
  float* wbuf = (float*)smem;                                   // 4352 f
  unsigned int* xpk = (unsigned int*)(smem + 17408);            // 8*68*XS
  float* prm = (float*)(smem + 17408 + 43520);                  // 768 f
  unsigned short* sgq = (unsigned short*)(smem + 17408 + 43520 + 3072);  // 8*32
  // ---- phase 0: ball query for this block's 8 centers (2 per wave)
  {
#pragma clang fp contract(off)
    const int lane = tid & 63;
    const int wvid = tid >> 6;
#pragma unroll 1
    for (int cc = 2 * wvid; cc < 2 * wvid + 2; ++cc) {
      const int sgg = j * 8 + cc;
      const int b = sgg >> 10, s = sgg & 1023;
      const float* xb = xyz + (size_t)b * NN * 3;
      const int ci = (int)fps_g[b * NP + s] & (NN - 1);
      const float cx = xb[ci * 3 + 0];
      const float cy = xb[ci * 3 + 1];
      const float cz = xb[ci * 3 + 2];
      const float nn = (cx * cx + cy * cy) + cz * cz;
      const float r2 = 0.04f;
      int total = 0;
      int first = -1;
      for (int c = 0; c < NN / 64 && total < NSAMP; ++c) {
        int i = (c << 6) + lane;
        float x = xb[i * 3 + 0];
        float y = xb[i * 3 + 1];
        float z = xb[i * 3 + 2];
        float pp = (x * x + y * y) + z * z;
        float dt = (x * cx + y * cy) + z * cz;
        float sq = (nn + pp) - 2.0f * dt;  // exact ref formula; self-dist == 0
        bool inb = !(sq > r2);
        unsigned long long m = __ballot(inb);
        if (first < 0 && m) first = (c << 6) + (__ffsll((unsigned long long)m) - 1);
        int before = __popcll(m & ((1ull << lane) - 1ull));
        int slot = total + before;
        if (inb && slot < NSAMP) sgq[cc * NSAMP + slot] = (unsigned short)i;
        total += (int)__popcll(m);
      }
      int cnt = total < NSAMP ? total : NSAMP;
      unsigned short fill = (unsigned short)(first < 0 ? 0 : first);
      if (lane >= cnt && lane < NSAMP) sgq[cc * NSAMP + lane] = fill;
    }
  }
  __syncthreads();
  // ---- phase 1: params + gather + W0 staging
  const float bnsc = 1.0f / sqrtf(1.001f);
  if (tid < 64) {
    prm[tid] = b0[tid];       prm[64 + tid] = g0[tid] * bnsc;  prm[128 + tid] = be0[tid];
    prm[192 + tid] = b1[tid]; prm[256 + tid] = g1[tid] * bnsc; prm[320 + tid] = be1[tid];
  }
  if (tid < 128) {
    prm[384 + tid] = b2[tid]; prm[512 + tid] = g2[tid] * bnsc; prm[640 + tid] = be2[tid];
  }
  if (tid < 128) {
    const int cbg = tid >> 4, rp = tid & 15;
    const int sgg = j * 8 + cbg;
    const int bg = sgg >> 10, sg = sgg & 1023;
    const int i0 = (int)sgq[cbg * NSAMP + 2 * rp] & (NN - 1);
    const int i1 = (int)sgq[cbg * NSAMP + 2 * rp + 1] & (NN - 1);
    const int ci = (int)fps_g[bg * NP + sg] & (NN - 1);
    const float* xb = xyz + (size_t)bg * NN * 3;
    unsigned int* xc = &xpk[(cbg * 68) * XS + rp];
    const float cx = xb[ci * 3], cy = xb[ci * 3 + 1], cz = xb[ci * 3 + 2];
    xc[0 * XS] = packbf(xb[i0 * 3] - cx,     xb[i1 * 3] - cx);
    xc[1 * XS] = packbf(xb[i0 * 3 + 1] - cy, xb[i1 * 3 + 1] - cy);
    xc[2 * XS] = packbf(xb[i0 * 3 + 2] - cz, xb[i1 * 3 + 2] - cz);
    const float4* p0 = (const float4*)(points + ((size_t)bg * NN + i0) * CIN);
    const float4* p1 = (const float4*)(points + ((size_t)bg * NN + i1) * CIN);
#pragma unroll 4
    for (int kk = 0; kk < 16; ++kk) {
      float4 a = p0[kk], c = p1[kk];
      xc[(3 + 4 * kk) * XS] = packbf(a.x, c.x);
      xc[(4 + 4 * kk) * XS] = packbf(a.y, c.y);
      xc[(5 + 4 * kk) * XS] = packbf(a.z, c.z);
      xc[(6 + 4 * kk) * XS] = packbf(a.w, c.w);
    }
  } else {
    for (int i = tid - 128; i < 67 * 64; i += 128) wbuf[i] = W0[i];
  }
  const int cb = tid >> 5, rg = (tid >> 3) & 3, cg = tid & 7;
  const int sgc = j * 8 + cb;
  const int bc = sgc >> 10, sc = sgc & 1023;
  const unsigned int* xrow = &xpk[(cb * 68) * XS + rg * 4];
  float acc[64];
  auto kstep = [&](int k) {
    uint4 xp = *(const uint4*)(xrow + k * XS);
    float xr[8] = {lo2f(xp.x), hi2f(xp.x), lo2f(xp.y), hi2f(xp.y),
                   lo2f(xp.z), hi2f(xp.z), lo2f(xp.w), hi2f(xp.w)};
    float4 wa = *(const float4*)&wbuf[k * 64 + cg * 8];
    float4 wc = *(const float4*)&wbuf[k * 64 + cg * 8 + 4];
#pragma unroll
    for (int r = 0; r < 8; ++r) {
      acc[r * 8 + 0] = fmaf(xr[r], wa.x, acc[r * 8 + 0]);
      acc[r * 8 + 1] = fmaf(xr[r], wa.y, acc[r * 8 + 1]);
      acc[r * 8 + 2] = fmaf(xr[r], wa.z, acc[r * 8 + 2]);
      acc[r * 8 + 3] = fmaf(xr[r], wa.w, acc[r * 8 + 3]);
      acc[r * 8 + 4] = fmaf(xr[r], wc.x, acc[r * 8 + 4]);
      acc[r * 8 + 5] = fmaf(xr[r], wc.y, acc[r * 8 + 5]);
      acc[r * 8 + 6] = fmaf(xr[r], wc.z, acc[r * 8 + 6]);
      acc[r * 8 + 7] = fmaf(xr[r], wc.w, acc[r * 8 + 7]);
    }
  };
  auto hwrite = [&](int pofs) {
#pragma unroll
    for (int c = 0; c < 8; ++c) {
      int cl = cg * 8 + c;
      float bia = prm[pofs + cl], gg = prm[pofs + 64 + cl], bb = prm[pofs + 128 + cl];
      unsigned int* hc = &xpk[(cb * 68 + cl) * XS + rg * 4];
#pragma unroll
      for (int i = 0; i < 4; ++i) {
        float za = acc[(2 * i) * 8 + c] + bia;
        za = za > 0.f ? za : 0.f;
        za = za * gg + bb;
        float zb = acc[(2 * i + 1) * 8 + c] + bia;
        zb = zb > 0.f ? zb : 0.f;
        zb = zb * gg + bb;
        hc[i] = packbf(za, zb);
      }
    }
  };
  __syncthreads();
#pragma unroll
  for (int i = 0; i < 64; ++i) acc[i] = 0.f;
#pragma unroll 2
  for (int k = 0; k < 67; ++k) kstep(k);
  __syncthreads();
  hwrite(0);
  for (int i = tid; i < 64 * 64; i += 256) wbuf[i] = W1[i];
  __syncthreads();
#pragma unroll
  for (int i = 0; i < 64; ++i) acc[i] = 0.f;
#pragma unroll 2
  for (int k = 0; k < 64; ++k) kstep(k);
  __syncthreads();
  hwrite(192);
  for (int i = tid; i < 64 * 64; i += 256) wbuf[i] = W2[(i >> 6) * C3 + (i & 63)];
  __syncthreads();
  float* outp = out_feat + (size_t)(bc * NP + sc) * C3;
#pragma unroll 1
  for (int half = 0; half < 2; ++half) {
    if (half) {
      __syncthreads();
      for (int i = tid; i < 64 * 64; i += 256)
        wbuf[i] = W2[(i >> 6) * C3 + 64 + (i & 63)];
      __syncthreads();
    }
#pragma unroll
    for (int i = 0; i < 64; ++i) acc[i] = 0.f;
#pragma unroll 2
    for (int k = 0; k < 64; ++k) kstep(k);
    float vout[8];
#pragma unroll
    for (int c = 0; c < 8; ++c) {
      int cl = half * 64 + cg * 8 + c;
      float bia = prm[384 + cl], gg = prm[512 + cl], bb = prm[640 + cl];
      float mmax = -3.4e38f;
#pragma unroll
      for (int r = 0; r < 8; ++r) {
        float z = acc[r * 8 + c] + bia;
        z = z > 0.f ? z : 0.f;
        z = z * gg + bb;
        mmax = fmaxf(mmax, z);
      }
      mmax = fmaxf(mmax, __shfl_xor(mmax, 8, 64));
      mmax = fmaxf(mmax, __shfl_xor(mmax, 16, 64));
      vout[c] = mmax;
    }
    if (rg == 0) {
      *(float4*)(outp + half * 64 + cg * 8) =
          make_float4(vout[0], vout[1], vout[2], vout[3]);
      *(float4*)(outp + half * 64 + cg * 8 + 4) =
          make_float4(vout[4], vout[5], vout[6], vout[7]);
    }
  }
}

extern "C" void kernel_launch(void* const* d_in, const int* in_sizes, int n_in,
                              void* d_out, int out_size, void* d_ws, size_t ws_size,
                              hipStream_t stream) {
  const float* xyz = (const float*)d_in[0];
  const float* points = (const float*)d_in[1];
  const float* W0 = (const float*)d_in[2];
  const float* b0 = (const float*)d_in[3];
  const float* g0 = (const float*)d_in[4];
  const float* be0 = (const float*)d_in[5];
  const float* W1 = (const float*)d_in[6];
  const float* b1 = (const float*)d_in[7];
  const float* g1 = (const float*)d_in[8];
  const float* be1 = (const float*)d_in[9];
  const float* W2 = (const float*)d_in[10];
  const float* b2 = (const float*)d_in[11];
  const float* g2 = (const float*)d_in[12];
  const float* be2 = (const float*)d_in[13];
  float* out = (float*)d_out;
  unsigned short* fps = (unsigned short*)d_ws;                  // 16 KB
  int* progress = (int*)((char*)d_ws + 16 * 1024);              // 8 ints
  fused_kernel<<<NB + NB * NP / 8, 256, 0, stream>>>(
      xyz, points, fps, progress, W0, b0, g0, be0, W1, b1, g1, be1,
      W2, b2, g2, be2, out, out + (size_t)NB * NP * 3);
}